// Round 7
// baseline (150.121 us; speedup 1.0000x reference)
//
#include <hip/hip_runtime.h>
#include <hip/hip_bf16.h>
#include <stdint.h>
#include <stddef.h>

// Problem constants (from reference). Harness dtype: fp32 in / fp32 out
// (verified round 2: WRITE_SIZE ~90 MB = 2048*10788*4B).
#define NUM_FEATURES 256
#define NUM_PIDS 5532
#define CQ_SIZE 5000
#define N_NONID 256
#define N_ROWS 2048
#define N_COLS (NUM_PIDS + CQ_SIZE + N_NONID)   // 10788
#define OIM_SCALAR 30.0f

// Tile config: 128x128 tile, BK=32, 4 waves (2x2) each computing 64x64.
#define BM 128
#define BN 128
#define BK 32
#define KITERS (NUM_FEATURES / BK)   // 8

// XCD swizzle: 85 n-tiles padded to 88 = 8 XCDs * 11 tiles.
#define NT_PER_XCD 11
#define N_TILES 85
#define M_TILES 16
#define GRID_BLOCKS (8 * NT_PER_XCD * M_TILES)   // 1408 (48 dummy blocks early-exit)

typedef __bf16 bf16_t;
typedef __bf16 bf16x4 __attribute__((ext_vector_type(4)));
typedef __bf16 bf16x8 __attribute__((ext_vector_type(8)));   // MFMA A/B frag
typedef float f32x4 __attribute__((ext_vector_type(4)));     // MFMA C/D frag; also
                                                             // clang vector type ->
                                                             // legal for
                                                             // __builtin_nontemporal_store
                                                             // (HIP float4 struct is NOT)

#define SP 68   // epilogue LDS row stride in dwords (64 + 4 pad; 16B-aligned)

__global__ __launch_bounds__(256)
void oim_gemm_kernel(const float* __restrict__ A,      // [2048][256]
                     const float* __restrict__ lut,    // [5532][256]
                     const float* __restrict__ cq,     // [5000][256]
                     const float* __restrict__ nonid,  // [256][256]
                     float* __restrict__ out) {        // [2048][10788]
    // 32 KB: As/Bs double buffers during K-loop; reused for epilogue transpose.
    __shared__ __align__(16) char smem[2 * BM * BK * 2 * 2];
    bf16_t* const As = (bf16_t*)smem;                       // [2][BM*BK]
    bf16_t* const Bs = (bf16_t*)(smem + 2 * BM * BK * 2);   // [2][BM*BK]

    // --- XCD-slab block swizzle ---
    const int id  = blockIdx.x;
    const int xcd = id & 7;
    const int l   = id >> 3;                  // 0..175
    const int nt  = xcd * NT_PER_XCD + l % NT_PER_XCD;
    const int mt  = l / NT_PER_XCD;           // 0..15
    if (nt >= N_TILES) return;                // dummy block (uniform, pre-barrier)
    const int m0 = mt * BM;
    const int n0 = nt * BN;

    const int tid  = threadIdx.x;
    const int wid  = tid >> 6;
    const int lane = tid & 63;

    // --- staging coords: each thread loads 4x float4 of A and of B per k-tile
    const int srow = tid >> 3;                // 0..31
    const int skk  = (tid & 7) * 4;           // 0,4,..,28

    const float* arow[4];
    const float* brow[4];
    #pragma unroll
    for (int j = 0; j < 4; ++j) {
        const int rm = m0 + srow + j * 32;
        arow[j] = A + (size_t)rm * NUM_FEATURES + skk;
        int r = n0 + srow + j * 32;
        r = r < (N_COLS - 1) ? r : (N_COLS - 1);   // clamp tail (stores guarded)
        const float* src;
        if (r < NUM_PIDS)                 src = lut   + (size_t)r * NUM_FEATURES;
        else if (r < NUM_PIDS + CQ_SIZE)  src = cq    + (size_t)(r - NUM_PIDS) * NUM_FEATURES;
        else                              src = nonid + (size_t)(r - NUM_PIDS - CQ_SIZE) * NUM_FEATURES;
        brow[j] = src + skk;
    }

    // --- MFMA fragment coords (verified m89/m91) ---
    const int wave_m = (wid >> 1) * 64;
    const int wave_n = (wid & 1) * 64;
    const int fr = lane & 15;                 // A/B frag: m (or n) = lane&15
    const int fk = (lane >> 4) * 8;           // k = (lane>>4)*8 + j

    f32x4 acc[4][4] = {};

    // --- prologue: prefetch k-tile 0 into registers ---
    f32x4 areg[4], breg[4];
    #pragma unroll
    for (int j = 0; j < 4; ++j) {
        areg[j] = *(const f32x4*)arow[j];
        breg[j] = *(const f32x4*)brow[j];
        arow[j] += BK;
        brow[j] += BK;
    }

    // --- single-barrier double-buffered K-loop (fully unrolled, r5) ---
    // Order per iter: cvt+write LDS(kt) -> ISSUE next global loads (regs only,
    // no LDS hazard) -> barrier -> ds_read frags + MFMA.
    #pragma unroll
    for (int kt = 0; kt < KITERS; ++kt) {
        bf16_t* const as = &As[(kt & 1) * BM * BK];
        bf16_t* const bs = &Bs[(kt & 1) * BM * BK];
        #pragma unroll
        for (int j = 0; j < 4; ++j) {
            const int ldix = (srow + j * 32) * BK + skk;
            bf16x4 ac = { (bf16_t)areg[j].x, (bf16_t)areg[j].y,
                          (bf16_t)areg[j].z, (bf16_t)areg[j].w };
            bf16x4 bc = { (bf16_t)breg[j].x, (bf16_t)breg[j].y,
                          (bf16_t)breg[j].z, (bf16_t)breg[j].w };
            *(bf16x4*)&as[ldix] = ac;
            *(bf16x4*)&bs[ldix] = bc;
        }
        if (kt < KITERS - 1) {                // compile-time (full unroll)
            #pragma unroll
            for (int j = 0; j < 4; ++j) {
                areg[j] = *(const f32x4*)arow[j];
                breg[j] = *(const f32x4*)brow[j];
                arow[j] += BK;
                brow[j] += BK;
            }
        }
        __syncthreads();

        bf16x8 af[4], bfr[4];
        #pragma unroll
        for (int t = 0; t < 4; ++t) {
            af[t]  = *(const bf16x8*)&as[(wave_m + t * 16 + fr) * BK + fk];
            bfr[t] = *(const bf16x8*)&bs[(wave_n + t * 16 + fr) * BK + fk];
        }
        #pragma unroll
        for (int tm = 0; tm < 4; ++tm)
            #pragma unroll
            for (int tn = 0; tn < 4; ++tn)
                acc[tm][tn] = __builtin_amdgcn_mfma_f32_16x16x32_bf16(
                    af[tm], bfr[tn], acc[tm][tn], 0, 0, 0);
        // no second barrier: double-buffer parity + next iteration's barrier
        // order writes of tile kt+2 after all reads of tile kt.
    }

    // =====================================================================
    // Epilogue v2: per-wave LDS transpose -> full-cacheline nontemporal
    // stores. Rationale (r2/r4/r5 counters): scalar epilogue = 64B segments;
    // plain stores forced C through L2, evicting A/B slabs (FETCH 89 MB vs
    // 13 ideal); nontemporal on 64B segments amplified writes 1.67x (r4).
    // Here each store instr covers 4 rows x 256 B contiguous, 16B-aligned
    // -> full 128B lines -> nontemporal is safe AND keeps C out of L2.
    // =====================================================================
    __syncthreads();   // all K-loop ds_reads complete before LDS reuse
    float* const ep = (float*)smem + wid * (16 * SP);   // per-wave 16-row slice
    const int q  = lane >> 4;
    const int c4 = lane & 15;
    #pragma unroll
    for (int tm = 0; tm < 4; ++tm) {
        // scatter this 16x64 accumulator slice into LDS (C/D layout:
        // col=lane&15 (+16*tn), row=(lane>>4)*4+i  — verified m89/m91)
        #pragma unroll
        for (int tn = 0; tn < 4; ++tn)
            #pragma unroll
            for (int i = 0; i < 4; ++i)
                ep[(q * 4 + i) * SP + tn * 16 + fr] = acc[tm][tn][i] * OIM_SCALAR;
        // gather rows as float4: per instr 64 lanes = 4 rows x 16 float4
        // (256 B contiguous per row). Per-wave region: DS ops of one wave
        // execute in order; compiler inserts lgkmcnt for the RAW dep.
        #pragma unroll
        for (int s = 0; s < 4; ++s) {
            const int r_l = s * 4 + q;
            f32x4 v = *(const f32x4*)&ep[r_l * SP + c4 * 4];
            const int row = m0 + wave_m + tm * 16 + r_l;
            const int col = n0 + wave_n + c4 * 4;
            if (col + 3 < N_COLS) {   // tail: 36 cols = 9 full float4s, no partial
                __builtin_nontemporal_store(
                    v, (f32x4*)&out[(size_t)row * N_COLS + col]);
            }
        }
    }
}

extern "C" void kernel_launch(void* const* d_in, const int* in_sizes, int n_in,
                              void* d_out, int out_size, void* d_ws, size_t ws_size,
                              hipStream_t stream) {
    // setup_inputs() order:
    // 0: inputs [2048,256], 1: non_id_feat [256,256], 2: lut [5532,256],
    // 3: cq [5000,256], 4: first_pos_sample, 5: second_pos_sample,
    // 6: targets (int), 7: belong_to_first_half, 8: header
    const float* inputs = (const float*)d_in[0];
    const float* nonid  = (const float*)d_in[1];
    const float* lut    = (const float*)d_in[2];
    const float* cq     = (const float*)d_in[3];
    float* out = (float*)d_out;

    oim_gemm_kernel<<<dim3(GRID_BLOCKS), 256, 0, stream>>>(inputs, lut, cq, nonid, out);
}